// Round 1
// baseline (2879.777 us; speedup 1.0000x reference)
//
#include <hip/hip_runtime.h>

#define NN 100000
#define NE 3200000
#define HD 20
#define EHD 64
#define EOUTD 10

// ---------------- zero workspace ----------------
__global__ void zero_kernel(float* __restrict__ p, int n) {
    int i = blockIdx.x * blockDim.x + threadIdx.x;
    if (i < n) p[i] = 0.0f;
}

// ---------------- edge MLP (recomputed in both passes; pure fn of d) ----------
__device__ __forceinline__ void edge_mlp(float d,
                                         const float* __restrict__ W1,
                                         const float* __restrict__ b1,
                                         const float* __restrict__ W2,
                                         const float* __restrict__ b2,
                                         float m[EOUTD]) {
    #pragma unroll
    for (int j = 0; j < EOUTD; ++j) m[j] = b2[j];
    for (int k = 0; k < EHD; ++k) {
        float h = fmaxf(fmaf(d, W1[k], b1[k]), 0.0f);
        #pragma unroll
        for (int j = 0; j < EOUTD; ++j)
            m[j] = fmaf(h, W2[k * EOUTD + j], m[j]);
    }
    // caller applies final relu
}

// ---------------- pass 1: sum_w[src] += comb(e) ----------------
__global__ void pass1_kernel(const float* __restrict__ ea,
                             const int* __restrict__ ei,
                             const float* __restrict__ W1,
                             const float* __restrict__ b1,
                             const float* __restrict__ W2,
                             const float* __restrict__ b2,
                             float* __restrict__ sum_w) {
    int e = blockIdx.x * blockDim.x + threadIdx.x;
    if (e >= NE) return;
    float d = ea[e];
    int src = ei[e];
    float m[EOUTD];
    edge_mlp(d, W1, b1, W2, b2, m);
    int idx = (int)d;           // d in (0,10]; bucket = min(int(d/1.0), 9)
    if (idx > 9) idx = 9;
    float* swp = sum_w + (size_t)src * HD;
    atomicAdd(&swp[idx], 1.0f);   // one-hot part: exactly one nonzero
    #pragma unroll
    for (int j = 0; j < EOUTD; ++j) {
        float v = fmaxf(m[j], 0.0f);
        if (v != 0.0f) atomicAdd(&swp[10 + j], v);
    }
}

// ---------------- pass 2: sum_feat[src] += rho * w_tilde ----------------
__global__ void pass2_kernel(const float* __restrict__ ea,
                             const int* __restrict__ ei,
                             const float* __restrict__ x,
                             const float* __restrict__ W1,
                             const float* __restrict__ b1,
                             const float* __restrict__ W2,
                             const float* __restrict__ b2,
                             const float* __restrict__ pa,
                             const float* __restrict__ pb,
                             const float* __restrict__ sum_w,
                             float* __restrict__ sum_feat) {
    int e = blockIdx.x * blockDim.x + threadIdx.x;
    if (e >= NE) return;
    float d = ea[e];
    int src = ei[e];
    int dst = ei[NE + e];
    float m[EOUTD];
    edge_mlp(d, W1, b1, W2, b2, m);
    int idx = (int)d;
    if (idx > 9) idx = 9;
    float a = pa[0];
    float b = pb[0];
    float one_minus_a = 1.0f - a;

    const float* swp = sum_w + (size_t)src * HD;
    const float* xsp = x + (size_t)src * 2 * HD;   // x[src,0,:]
    const float* xdp = x + (size_t)dst * 2 * HD;   // x[dst,0,:]
    float* sfp = sum_feat + (size_t)src * HD;

    #pragma unroll
    for (int k = 0; k < HD; ++k) {
        float comb = (k < 10) ? ((k == idx) ? 1.0f : 0.0f)
                              : fmaxf(m[k - 10], 0.0f);
        float swk = swp[k];
        float wt = (swk != 0.0f) ? (comb / swk) : 0.01f;
        if (wt != 0.0f) {
            float base = fabsf(a * xsp[k] - one_minus_a * xdp[k]);
            float r = (base > 0.0f) ? exp2f(b * log2f(base)) : 0.0f;
            float v = r * wt;
            if (v != 0.0f) atomicAdd(&sfp[k], v);
        }
    }
}

// ---------------- pass 3: node epilogue ----------------
__global__ void pass3_kernel(const float* __restrict__ x,
                             const float* __restrict__ sum_feat,
                             const float* __restrict__ g1,
                             const float* __restrict__ g2,
                             const float* __restrict__ bias,
                             float* __restrict__ out) {
    int n = blockIdx.x * blockDim.x + threadIdx.x;
    if (n >= NN) return;
    const float* xp = x + (size_t)n * 2 * HD;
    const float* sfp = sum_feat + (size_t)n * HD;
    float xs[HD], sf[HD];
    #pragma unroll
    for (int k = 0; k < HD; ++k) { xs[k] = xp[k]; sf[k] = sfp[k]; }
    float* op = out + (size_t)n * 2 * HD;
    for (int i = 0; i < HD; ++i) {
        float acc = bias[i];
        #pragma unroll
        for (int j = 0; j < HD; ++j) {
            acc = fmaf(xs[j], g1[i * HD + j], acc);
            acc = fmaf(sf[j], g2[i * HD + j], acc);
        }
        op[i] = fmaxf(acc, 0.0f);
        op[HD + i] = sf[i];
    }
}

extern "C" void kernel_launch(void* const* d_in, const int* in_sizes, int n_in,
                              void* d_out, int out_size, void* d_ws, size_t ws_size,
                              hipStream_t stream) {
    const float* x    = (const float*)d_in[0];
    const int*   ei   = (const int*)d_in[1];
    const float* ea   = (const float*)d_in[2];
    const float* pa   = (const float*)d_in[3];
    const float* pb   = (const float*)d_in[4];
    const float* g1   = (const float*)d_in[5];
    const float* g2   = (const float*)d_in[6];
    const float* bias = (const float*)d_in[7];
    const float* W1   = (const float*)d_in[8];
    const float* b1   = (const float*)d_in[9];
    const float* W2   = (const float*)d_in[10];
    const float* b2   = (const float*)d_in[11];
    float* out = (float*)d_out;

    float* sum_w    = (float*)d_ws;                       // [NN, 20]
    float* sum_feat = sum_w + (size_t)NN * HD;            // [NN, 20]

    int nz = 2 * NN * HD;
    zero_kernel<<<(nz + 255) / 256, 256, 0, stream>>>(sum_w, nz);

    pass1_kernel<<<(NE + 255) / 256, 256, 0, stream>>>(ea, ei, W1, b1, W2, b2, sum_w);

    pass2_kernel<<<(NE + 255) / 256, 256, 0, stream>>>(ea, ei, x, W1, b1, W2, b2,
                                                       pa, pb, sum_w, sum_feat);

    pass3_kernel<<<(NN + 255) / 256, 256, 0, stream>>>(x, sum_feat, g1, g2, bias, out);
}

// Round 5
// 898.423 us; speedup vs baseline: 3.2054x; 3.2054x over previous
//
#include <hip/hip_runtime.h>

#define NN 100000
#define NE 3200000
#define HD 20
#define EHD 64
#define EOUTD 10
#define SCAN_B 1024
#define NBLK ((NN + SCAN_B - 1) / SCAN_B)   // 98

// ---------------- zero int buffer ----------------
__global__ void zero_ints(int* __restrict__ p, int n) {
    int i = blockIdx.x * blockDim.x + threadIdx.x;
    if (i < n) p[i] = 0;
}

// ---------------- histogram of src ----------------
__global__ void hist_kernel(const int* __restrict__ ei, int* __restrict__ cnt) {
    int e = blockIdx.x * blockDim.x + threadIdx.x;
    if (e >= NE) return;
    atomicAdd(&cnt[ei[e]], 1);
}

// ---------------- scan A: per-block exclusive scan ----------------
__global__ void scanA_kernel(const int* __restrict__ cnt,
                             int* __restrict__ offsets,
                             int* __restrict__ bsum) {
    __shared__ int s[SCAN_B];
    int t = threadIdx.x;
    int i = blockIdx.x * SCAN_B + t;
    int v = (i < NN) ? cnt[i] : 0;
    s[t] = v;
    __syncthreads();
    for (int off = 1; off < SCAN_B; off <<= 1) {
        int add = (t >= off) ? s[t - off] : 0;
        __syncthreads();
        s[t] += add;
        __syncthreads();
    }
    int incl = s[t];
    if (i < NN) offsets[i] = incl - v;          // exclusive partial
    if (t == SCAN_B - 1) bsum[blockIdx.x] = incl;
}

// ---------------- scan B: serial scan of 98 block sums ----------------
__global__ void scanB_kernel(int* __restrict__ bsum, int* __restrict__ offsets) {
    if (blockIdx.x == 0 && threadIdx.x == 0) {
        int run = 0;
        for (int b = 0; b < NBLK; ++b) {
            int t = bsum[b];
            bsum[b] = run;
            run += t;
        }
        offsets[NN] = run;   // == NE
    }
}

// ---------------- scan C: add block bases, copy to cursor ----------------
__global__ void scanC_kernel(int* __restrict__ offsets,
                             const int* __restrict__ bsum,
                             int* __restrict__ cursor) {
    int i = blockIdx.x * blockDim.x + threadIdx.x;
    if (i >= NN) return;
    int f = offsets[i] + bsum[i >> 10];
    offsets[i] = f;
    cursor[i] = f;
}

// ---------------- scatter edges into CSR ----------------
__global__ void scatter_kernel(const int* __restrict__ ei,
                               const float* __restrict__ ea,
                               int* __restrict__ cursor,
                               int* __restrict__ csr_dst,
                               float* __restrict__ csr_d) {
    int e = blockIdx.x * blockDim.x + threadIdx.x;
    if (e >= NE) return;
    int src = ei[e];
    int pos = atomicAdd(&cursor[src], 1);
    csr_dst[pos] = ei[NE + e];
    csr_d[pos]   = ea[e];
}

// ---------------- node-owner kernel: sum_w, sum_feat, epilogue ----------------
__launch_bounds__(256)
__global__ void node_kernel(const int* __restrict__ offsets,
                            const int* __restrict__ csr_dst,
                            const float* __restrict__ csr_d,
                            const float* __restrict__ x,
                            const float* __restrict__ W1,
                            const float* __restrict__ b1,
                            const float* __restrict__ W2,
                            const float* __restrict__ b2,
                            const float* __restrict__ pa,
                            const float* __restrict__ pb,
                            const float* __restrict__ g1,
                            const float* __restrict__ g2,
                            const float* __restrict__ bias,
                            float* __restrict__ out) {
    __shared__ float sW1[EHD], sb1[EHD], sW2[EHD * EOUTD], sb2[EOUTD];
    __shared__ float sg1[HD * HD], sg2[HD * HD], sbias[HD];
    int tid = threadIdx.x;
    for (int i = tid; i < EHD; i += 256) { sW1[i] = W1[i]; sb1[i] = b1[i]; }
    for (int i = tid; i < EHD * EOUTD; i += 256) sW2[i] = W2[i];
    for (int i = tid; i < EOUTD; i += 256) sb2[i] = b2[i];
    for (int i = tid; i < HD * HD; i += 256) { sg1[i] = g1[i]; sg2[i] = g2[i]; }
    for (int i = tid; i < HD; i += 256) sbias[i] = bias[i];
    __syncthreads();

    int slot = tid >> 5;          // 8 nodes per 256-thread block
    int lane = tid & 31;
    int node = blockIdx.x * 8 + slot;
    if (node >= NN) return;

    int off0 = offsets[node];
    int deg  = offsets[node + 1] - off0;
    float a = pa[0], b = pb[0];
    float oma = 1.0f - a;

    // x[node, 0, :]
    float xs[HD];
    {
        const float4* xp = (const float4*)(x + (size_t)node * 2 * HD);
        #pragma unroll
        for (int q = 0; q < 5; ++q) {
            float4 v = xp[q];
            xs[4 * q] = v.x; xs[4 * q + 1] = v.y; xs[4 * q + 2] = v.z; xs[4 * q + 3] = v.w;
        }
    }

    // -------- phase 1: sum_w in registers --------
    float sw[HD];
    #pragma unroll
    for (int k = 0; k < HD; ++k) sw[k] = 0.0f;

    for (int i = lane; i < deg; i += 32) {
        float d = csr_d[off0 + i];
        float m[EOUTD];
        #pragma unroll
        for (int j = 0; j < EOUTD; ++j) m[j] = sb2[j];
        for (int k = 0; k < EHD; ++k) {
            float h = fmaxf(fmaf(d, sW1[k], sb1[k]), 0.0f);
            #pragma unroll
            for (int j = 0; j < EOUTD; ++j) m[j] = fmaf(h, sW2[k * EOUTD + j], m[j]);
        }
        int idx = (int)d; if (idx > 9) idx = 9;
        #pragma unroll
        for (int k = 0; k < 10; ++k) sw[k] += (k == idx) ? 1.0f : 0.0f;
        #pragma unroll
        for (int j = 0; j < EOUTD; ++j) sw[10 + j] += fmaxf(m[j], 0.0f);
    }
    // butterfly reduce within the 32-lane half-wave
    #pragma unroll
    for (int s = 16; s >= 1; s >>= 1) {
        #pragma unroll
        for (int k = 0; k < HD; ++k) sw[k] += __shfl_xor(sw[k], s, 32);
    }
    // invert: sw[k] -> 1/sw[k], or -1 marker when zero
    #pragma unroll
    for (int k = 0; k < HD; ++k) sw[k] = (sw[k] != 0.0f) ? (1.0f / sw[k]) : -1.0f;

    // -------- phase 2: sum_feat in registers --------
    float sf[HD];
    #pragma unroll
    for (int k = 0; k < HD; ++k) sf[k] = 0.0f;

    for (int i = lane; i < deg; i += 32) {
        float d = csr_d[off0 + i];
        int dst  = csr_dst[off0 + i];
        float m[EOUTD];
        #pragma unroll
        for (int j = 0; j < EOUTD; ++j) m[j] = sb2[j];
        for (int k = 0; k < EHD; ++k) {
            float h = fmaxf(fmaf(d, sW1[k], sb1[k]), 0.0f);
            #pragma unroll
            for (int j = 0; j < EOUTD; ++j) m[j] = fmaf(h, sW2[k * EOUTD + j], m[j]);
        }
        int idx = (int)d; if (idx > 9) idx = 9;

        float xd[HD];
        {
            const float4* xdp = (const float4*)(x + (size_t)dst * 2 * HD);
            #pragma unroll
            for (int q = 0; q < 5; ++q) {
                float4 v = xdp[q];
                xd[4 * q] = v.x; xd[4 * q + 1] = v.y; xd[4 * q + 2] = v.z; xd[4 * q + 3] = v.w;
            }
        }
        #pragma unroll
        for (int k = 0; k < HD; ++k) {
            float comb = (k < 10) ? ((k == idx) ? 1.0f : 0.0f) : fmaxf(m[k - 10], 0.0f);
            float rsw = sw[k];
            float wt = (rsw >= 0.0f) ? comb * rsw : 0.01f;
            if (wt != 0.0f) {
                float base = fabsf(a * xs[k] - oma * xd[k]);
                float r = (base > 0.0f) ? exp2f(b * log2f(base)) : 0.0f;
                sf[k] = fmaf(r, wt, sf[k]);
            }
        }
    }
    #pragma unroll
    for (int s = 16; s >= 1; s >>= 1) {
        #pragma unroll
        for (int k = 0; k < HD; ++k) sf[k] += __shfl_xor(sf[k], s, 32);
    }

    // -------- epilogue: out0 = relu(g1 x + g2 sf + bias); out1 = sf --------
    if (lane < HD) {
        float acc = sbias[lane];
        #pragma unroll
        for (int j = 0; j < HD; ++j) {
            acc = fmaf(xs[j], sg1[lane * HD + j], acc);
            acc = fmaf(sf[j], sg2[lane * HD + j], acc);
        }
        // extract sf[lane] with compile-time indices (avoid scratch)
        float myv = 0.0f;
        #pragma unroll
        for (int k = 0; k < HD; ++k) if (lane == k) myv = sf[k];
        float* op = out + (size_t)node * 2 * HD;
        op[lane]      = fmaxf(acc, 0.0f);
        op[HD + lane] = myv;
    }
}

extern "C" void kernel_launch(void* const* d_in, const int* in_sizes, int n_in,
                              void* d_out, int out_size, void* d_ws, size_t ws_size,
                              hipStream_t stream) {
    const float* x    = (const float*)d_in[0];
    const int*   ei   = (const int*)d_in[1];
    const float* ea   = (const float*)d_in[2];
    const float* pa   = (const float*)d_in[3];
    const float* pb   = (const float*)d_in[4];
    const float* g1   = (const float*)d_in[5];
    const float* g2   = (const float*)d_in[6];
    const float* bias = (const float*)d_in[7];
    const float* W1   = (const float*)d_in[8];
    const float* b1   = (const float*)d_in[9];
    const float* W2   = (const float*)d_in[10];
    const float* b2   = (const float*)d_in[11];
    float* out = (float*)d_out;

    // workspace layout (ints/floats are 4B)
    char* ws = (char*)d_ws;
    int*   offsets = (int*)ws;                          ws += ((NN + 1) * 4 + 124) / 128 * 128;
    int*   bsum    = (int*)ws;                          ws += (NBLK * 4 + 124) / 128 * 128;
    int*   cursor  = (int*)ws;                          ws += ((size_t)NN * 4 + 124) / 128 * 128;
    int*   csr_dst = (int*)ws;                          ws += (size_t)NE * 4;
    float* csr_d   = (float*)ws;                        ws += (size_t)NE * 4;

    zero_ints<<<(NN + 255) / 256, 256, 0, stream>>>(cursor, NN);
    hist_kernel<<<(NE + 255) / 256, 256, 0, stream>>>(ei, cursor);
    scanA_kernel<<<NBLK, SCAN_B, 0, stream>>>(cursor, offsets, bsum);
    scanB_kernel<<<1, 64, 0, stream>>>(bsum, offsets);
    scanC_kernel<<<(NN + 255) / 256, 256, 0, stream>>>(offsets, bsum, cursor);
    scatter_kernel<<<(NE + 255) / 256, 256, 0, stream>>>(ei, ea, cursor, csr_dst, csr_d);
    node_kernel<<<(NN + 7) / 8, 256, 0, stream>>>(offsets, csr_dst, csr_d, x,
                                                  W1, b1, W2, b2, pa, pb,
                                                  g1, g2, bias, out);
}

// Round 6
// 561.847 us; speedup vs baseline: 5.1256x; 1.5991x over previous
//
#include <hip/hip_runtime.h>

#define NN 100000
#define NE 3200000
#define HD 20
#define EHD 64
#define EOUTD 10
#define SCAN_B 1024
#define NBLK ((NN + SCAN_B - 1) / SCAN_B)   // 98

// ---------------- zero int buffer ----------------
__global__ void zero_ints(int* __restrict__ p, int n) {
    int i = blockIdx.x * blockDim.x + threadIdx.x;
    if (i < n) p[i] = 0;
}

// ---------------- histogram of src ----------------
__global__ void hist_kernel(const int* __restrict__ ei, int* __restrict__ cnt) {
    int e = blockIdx.x * blockDim.x + threadIdx.x;
    if (e >= NE) return;
    atomicAdd(&cnt[ei[e]], 1);
}

// ---------------- scan A: per-block exclusive scan ----------------
__global__ void scanA_kernel(const int* __restrict__ cnt,
                             int* __restrict__ offsets,
                             int* __restrict__ bsum) {
    __shared__ int s[SCAN_B];
    int t = threadIdx.x;
    int i = blockIdx.x * SCAN_B + t;
    int v = (i < NN) ? cnt[i] : 0;
    s[t] = v;
    __syncthreads();
    for (int off = 1; off < SCAN_B; off <<= 1) {
        int add = (t >= off) ? s[t - off] : 0;
        __syncthreads();
        s[t] += add;
        __syncthreads();
    }
    int incl = s[t];
    if (i < NN) offsets[i] = incl - v;          // exclusive partial
    if (t == SCAN_B - 1) bsum[blockIdx.x] = incl;
}

// ---------------- scan B: serial scan of 98 block sums ----------------
__global__ void scanB_kernel(int* __restrict__ bsum, int* __restrict__ offsets) {
    if (blockIdx.x == 0 && threadIdx.x == 0) {
        int run = 0;
        for (int b = 0; b < NBLK; ++b) {
            int t = bsum[b];
            bsum[b] = run;
            run += t;
        }
        offsets[NN] = run;   // == NE
    }
}

// ---------------- scan C: add block bases, copy to cursor ----------------
__global__ void scanC_kernel(int* __restrict__ offsets,
                             const int* __restrict__ bsum,
                             int* __restrict__ cursor) {
    int i = blockIdx.x * blockDim.x + threadIdx.x;
    if (i >= NN) return;
    int f = offsets[i] + bsum[i >> 10];
    offsets[i] = f;
    cursor[i] = f;
}

// ---------------- scatter edges into packed CSR (dst, d) ----------------
__global__ void scatter_kernel(const int* __restrict__ ei,
                               const float* __restrict__ ea,
                               int* __restrict__ cursor,
                               int2* __restrict__ csr_pk) {
    int e = blockIdx.x * blockDim.x + threadIdx.x;
    if (e >= NE) return;
    int src = ei[e];
    int pos = atomicAdd(&cursor[src], 1);
    int2 pk;
    pk.x = ei[NE + e];
    pk.y = __float_as_int(ea[e]);
    csr_pk[pos] = pk;
}

// ---------------- node-owner kernel: single algebraic pass + epilogue -------
// sum_feat[k] = S0[k]!=0 ? S1[k]/S0[k] : 0.01*Sr[k]
//   S0[k] = sum_e comb_e[k], S1[k] = sum_e rho_e[k]*comb_e[k], Sr = sum_e rho_e[k]
__launch_bounds__(256)
__global__ void node_kernel(const int* __restrict__ offsets,
                            const int2* __restrict__ csr_pk,
                            const float* __restrict__ x,
                            const float* __restrict__ W1,
                            const float* __restrict__ b1,
                            const float* __restrict__ W2,
                            const float* __restrict__ b2,
                            const float* __restrict__ pa,
                            const float* __restrict__ pb,
                            const float* __restrict__ g1,
                            const float* __restrict__ g2,
                            const float* __restrict__ bias,
                            float* __restrict__ out) {
    int tid  = threadIdx.x;
    int grp  = tid >> 4;          // 16 nodes per 256-thread block
    int lane = tid & 15;
    int node = blockIdx.x * 16 + grp;
    if (node >= NN) return;

    int off0 = offsets[node];
    int deg  = offsets[node + 1] - off0;
    float a = pa[0], bb = pb[0];
    float oma = 1.0f - a;

    // x[node, 0, :] (kept in regs, reused every edge)
    float xs[HD];
    {
        const float4* xp = (const float4*)(x + (size_t)node * 2 * HD);
        #pragma unroll
        for (int q = 0; q < 5; ++q) {
            float4 v = xp[q];
            xs[4 * q] = v.x; xs[4 * q + 1] = v.y; xs[4 * q + 2] = v.z; xs[4 * q + 3] = v.w;
        }
    }

    float S0[HD], S1[HD], Sr[HD];
    #pragma unroll
    for (int k = 0; k < HD; ++k) { S0[k] = 0.0f; S1[k] = 0.0f; Sr[k] = 0.0f; }

    for (int i = lane; i < deg; i += 16) {
        int2 pk = csr_pk[off0 + i];
        int dst = pk.x;
        float d = __int_as_float(pk.y);

        // edge MLP — weights read via uniform (scalar) global loads, no LDS
        float m[EOUTD];
        #pragma unroll
        for (int j = 0; j < EOUTD; ++j) m[j] = b2[j];
        #pragma unroll 4
        for (int k = 0; k < EHD; ++k) {
            float h = fmaxf(fmaf(d, W1[k], b1[k]), 0.0f);
            #pragma unroll
            for (int j = 0; j < EOUTD; ++j) m[j] = fmaf(h, W2[k * EOUTD + j], m[j]);
        }
        int idx = (int)d; if (idx > 9) idx = 9;

        const float4* xdp = (const float4*)(x + (size_t)dst * 2 * HD);
        #pragma unroll
        for (int q = 0; q < 5; ++q) {
            float4 xv = xdp[q];
            #pragma unroll
            for (int t = 0; t < 4; ++t) {
                const int k = 4 * q + t;
                float xdk = (t == 0) ? xv.x : (t == 1) ? xv.y : (t == 2) ? xv.z : xv.w;
                float base = fabsf(a * xs[k] - oma * xdk);
                float rho = (base > 0.0f) ? exp2f(bb * log2f(base)) : 0.0f;
                Sr[k] += rho;
                float comb;
                if (k < 10) comb = (k == idx) ? 1.0f : 0.0f;
                else        comb = fmaxf(m[k - 10], 0.0f);
                S0[k] += comb;
                S1[k] = fmaf(rho, comb, S1[k]);
            }
        }
    }

    // butterfly reduce within the 16-lane group
    #pragma unroll
    for (int s = 8; s >= 1; s >>= 1) {
        #pragma unroll
        for (int k = 0; k < HD; ++k) {
            S0[k] += __shfl_xor(S0[k], s, 16);
            S1[k] += __shfl_xor(S1[k], s, 16);
            Sr[k] += __shfl_xor(Sr[k], s, 16);
        }
    }

    // finalize sum_feat
    float sf[HD];
    #pragma unroll
    for (int k = 0; k < HD; ++k)
        sf[k] = (S0[k] != 0.0f) ? (S1[k] / S0[k]) : (0.01f * Sr[k]);

    // epilogue: rows lane and lane+16; out0 = relu(g1 x + g2 sf + bias), out1 = sf
    float* op = out + (size_t)node * 2 * HD;
    {
        int r = lane;                       // rows 0..15
        float acc = bias[r];
        const float4* g1p = (const float4*)(g1 + r * HD);
        const float4* g2p = (const float4*)(g2 + r * HD);
        #pragma unroll
        for (int q = 0; q < 5; ++q) {
            float4 w1 = g1p[q], w2 = g2p[q];
            acc = fmaf(xs[4 * q], w1.x, acc); acc = fmaf(sf[4 * q], w2.x, acc);
            acc = fmaf(xs[4 * q + 1], w1.y, acc); acc = fmaf(sf[4 * q + 1], w2.y, acc);
            acc = fmaf(xs[4 * q + 2], w1.z, acc); acc = fmaf(sf[4 * q + 2], w2.z, acc);
            acc = fmaf(xs[4 * q + 3], w1.w, acc); acc = fmaf(sf[4 * q + 3], w2.w, acc);
        }
        float myv = 0.0f;
        #pragma unroll
        for (int k = 0; k < HD; ++k) if (r == k) myv = sf[k];
        op[r] = fmaxf(acc, 0.0f);
        op[HD + r] = myv;
    }
    if (lane < HD - 16) {                   // rows 16..19 on lanes 0..3
        int r = lane + 16;
        float acc = bias[r];
        const float4* g1p = (const float4*)(g1 + r * HD);
        const float4* g2p = (const float4*)(g2 + r * HD);
        #pragma unroll
        for (int q = 0; q < 5; ++q) {
            float4 w1 = g1p[q], w2 = g2p[q];
            acc = fmaf(xs[4 * q], w1.x, acc); acc = fmaf(sf[4 * q], w2.x, acc);
            acc = fmaf(xs[4 * q + 1], w1.y, acc); acc = fmaf(sf[4 * q + 1], w2.y, acc);
            acc = fmaf(xs[4 * q + 2], w1.z, acc); acc = fmaf(sf[4 * q + 2], w2.z, acc);
            acc = fmaf(xs[4 * q + 3], w1.w, acc); acc = fmaf(sf[4 * q + 3], w2.w, acc);
        }
        float myv = 0.0f;
        #pragma unroll
        for (int k = 0; k < HD; ++k) if (r == k) myv = sf[k];
        op[r] = fmaxf(acc, 0.0f);
        op[HD + r] = myv;
    }
}

extern "C" void kernel_launch(void* const* d_in, const int* in_sizes, int n_in,
                              void* d_out, int out_size, void* d_ws, size_t ws_size,
                              hipStream_t stream) {
    const float* x    = (const float*)d_in[0];
    const int*   ei   = (const int*)d_in[1];
    const float* ea   = (const float*)d_in[2];
    const float* pa   = (const float*)d_in[3];
    const float* pb   = (const float*)d_in[4];
    const float* g1   = (const float*)d_in[5];
    const float* g2   = (const float*)d_in[6];
    const float* bias = (const float*)d_in[7];
    const float* W1   = (const float*)d_in[8];
    const float* b1   = (const float*)d_in[9];
    const float* W2   = (const float*)d_in[10];
    const float* b2   = (const float*)d_in[11];
    float* out = (float*)d_out;

    // workspace layout
    char* ws = (char*)d_ws;
    int*  offsets = (int*)ws;                     ws += ((NN + 1) * 4 + 124) / 128 * 128;
    int*  bsum    = (int*)ws;                     ws += (NBLK * 4 + 124) / 128 * 128;
    int*  cursor  = (int*)ws;                     ws += ((size_t)NN * 4 + 124) / 128 * 128;
    int2* csr_pk  = (int2*)ws;                    ws += (size_t)NE * 8;

    zero_ints<<<(NN + 255) / 256, 256, 0, stream>>>(cursor, NN);
    hist_kernel<<<(NE + 255) / 256, 256, 0, stream>>>(ei, cursor);
    scanA_kernel<<<NBLK, SCAN_B, 0, stream>>>(cursor, offsets, bsum);
    scanB_kernel<<<1, 64, 0, stream>>>(bsum, offsets);
    scanC_kernel<<<(NN + 255) / 256, 256, 0, stream>>>(offsets, bsum, cursor);
    scatter_kernel<<<(NE + 255) / 256, 256, 0, stream>>>(ei, ea, cursor, csr_pk);
    node_kernel<<<(NN + 15) / 16, 256, 0, stream>>>(offsets, csr_pk, x,
                                                    W1, b1, W2, b2, pa, pb,
                                                    g1, g2, bias, out);
}

// Round 8
// 328.790 us; speedup vs baseline: 8.7587x; 1.7088x over previous
//
#include <hip/hip_runtime.h>

#define NN 100000
#define NE 3200000
#define HD 20
#define EHD 64
#define EOUTD 10
#define SCAN_B 1024
#define NBLK ((NN + SCAN_B - 1) / SCAN_B)   // 98
#define TBINS 4096
#define TROW 12                              // 10 values + 2 pad -> 48B rows, 16B aligned

// ---------------- zero int buffer ----------------
__global__ void zero_ints(int* __restrict__ p, int n) {
    int i = blockIdx.x * blockDim.x + threadIdx.x;
    if (i < n) p[i] = 0;
}

// ---------------- histogram of src + per-edge rank ----------------
__global__ void hist_rank_kernel(const int* __restrict__ ei,
                                 int* __restrict__ cnt,
                                 int* __restrict__ rank) {
    int e = blockIdx.x * blockDim.x + threadIdx.x;
    if (e >= NE) return;
    rank[e] = atomicAdd(&cnt[ei[e]], 1);
}

// ---------------- scan A: per-block exclusive scan ----------------
__global__ void scanA_kernel(const int* __restrict__ cnt,
                             int* __restrict__ offsets,
                             int* __restrict__ bsum) {
    __shared__ int s[SCAN_B];
    int t = threadIdx.x;
    int i = blockIdx.x * SCAN_B + t;
    int v = (i < NN) ? cnt[i] : 0;
    s[t] = v;
    __syncthreads();
    for (int off = 1; off < SCAN_B; off <<= 1) {
        int add = (t >= off) ? s[t - off] : 0;
        __syncthreads();
        s[t] += add;
        __syncthreads();
    }
    int incl = s[t];
    if (i < NN) offsets[i] = incl - v;          // exclusive partial
    if (t == SCAN_B - 1) bsum[blockIdx.x] = incl;
}

// ---------------- scan B: serial scan of 98 block sums ----------------
__global__ void scanB_kernel(int* __restrict__ bsum, int* __restrict__ offsets) {
    if (blockIdx.x == 0 && threadIdx.x == 0) {
        int run = 0;
        for (int b = 0; b < NBLK; ++b) {
            int t = bsum[b];
            bsum[b] = run;
            run += t;
        }
        offsets[NN] = run;   // == NE
    }
}

// ---------------- scan C: add block bases ----------------
__global__ void scanC_kernel(int* __restrict__ offsets,
                             const int* __restrict__ bsum) {
    int i = blockIdx.x * blockDim.x + threadIdx.x;
    if (i >= NN) return;
    offsets[i] += bsum[i >> 10];
}

// ---------------- MLP table: sample pre-relu mlp_out at 4097 points ---------
__global__ void table_kernel(const float* __restrict__ W1,
                             const float* __restrict__ b1,
                             const float* __restrict__ W2,
                             const float* __restrict__ b2,
                             float* __restrict__ tab) {
    int i = blockIdx.x * blockDim.x + threadIdx.x;
    if (i > TBINS) return;
    float d = (float)i * (10.0f / (float)TBINS);
    float m[EOUTD];
    #pragma unroll
    for (int j = 0; j < EOUTD; ++j) m[j] = b2[j];
    for (int k = 0; k < EHD; ++k) {
        float h = fmaxf(fmaf(d, W1[k], b1[k]), 0.0f);
        #pragma unroll
        for (int j = 0; j < EOUTD; ++j) m[j] = fmaf(h, W2[k * EOUTD + j], m[j]);
    }
    float* row = tab + (size_t)i * TROW;
    #pragma unroll
    for (int j = 0; j < EOUTD; ++j) row[j] = m[j];   // pre-relu (relu in consumer)
    row[10] = 0.0f; row[11] = 0.0f;
}

// ---------------- scatter edges into packed CSR (no atomics) ----------------
__global__ void scatter_kernel(const int* __restrict__ ei,
                               const float* __restrict__ ea,
                               const int* __restrict__ offsets,
                               const int* __restrict__ rank,
                               int2* __restrict__ csr_pk) {
    int e = blockIdx.x * blockDim.x + threadIdx.x;
    if (e >= NE) return;
    int src = ei[e];
    int pos = offsets[src] + rank[e];
    int2 pk;
    pk.x = ei[NE + e];
    pk.y = __float_as_int(ea[e]);
    csr_pk[pos] = pk;
}

// ---------------- node-owner kernel: single algebraic pass + epilogue -------
// sum_feat[k] = S0[k]!=0 ? S1[k]/S0[k] : 0.01*Sr[k]
__launch_bounds__(256)
__global__ void node_kernel(const int* __restrict__ offsets,
                            const int2* __restrict__ csr_pk,
                            const float* __restrict__ x,
                            const float* __restrict__ tab,
                            const float* __restrict__ pa,
                            const float* __restrict__ pb,
                            const float* __restrict__ g1,
                            const float* __restrict__ g2,
                            const float* __restrict__ bias,
                            float* __restrict__ out) {
    int tid  = threadIdx.x;
    int grp  = tid >> 4;          // 16 nodes per 256-thread block
    int lane = tid & 15;
    int node = blockIdx.x * 16 + grp;
    if (node >= NN) return;

    int off0 = offsets[node];
    int deg  = offsets[node + 1] - off0;
    float a = pa[0], bb = pb[0];
    float oma = 1.0f - a;

    float xs[HD];
    {
        const float4* xp = (const float4*)(x + (size_t)node * 2 * HD);
        #pragma unroll
        for (int q = 0; q < 5; ++q) {
            float4 v = xp[q];
            xs[4 * q] = v.x; xs[4 * q + 1] = v.y; xs[4 * q + 2] = v.z; xs[4 * q + 3] = v.w;
        }
    }

    float S0[HD], S1[HD], Sr[HD];
    #pragma unroll
    for (int k = 0; k < HD; ++k) { S0[k] = 0.0f; S1[k] = 0.0f; Sr[k] = 0.0f; }

    for (int i = lane; i < deg; i += 16) {
        int2 pk = csr_pk[off0 + i];
        int dst = pk.x;
        float d = __int_as_float(pk.y);

        // table-interpolated edge MLP (pre-relu values)
        float u = d * ((float)TBINS / 10.0f);
        int ti = (int)u; if (ti > TBINS - 1) ti = TBINS - 1;
        float f = u - (float)ti;
        const float4* t0 = (const float4*)(tab + (size_t)ti * TROW);
        float4 a0 = t0[0], a1 = t0[1], a2 = t0[2];
        float4 c0 = t0[3], c1 = t0[4], c2 = t0[5];   // next row (+12 floats = +3 float4)
        float m[EOUTD];
        m[0] = fmaf(f, c0.x - a0.x, a0.x);
        m[1] = fmaf(f, c0.y - a0.y, a0.y);
        m[2] = fmaf(f, c0.z - a0.z, a0.z);
        m[3] = fmaf(f, c0.w - a0.w, a0.w);
        m[4] = fmaf(f, c1.x - a1.x, a1.x);
        m[5] = fmaf(f, c1.y - a1.y, a1.y);
        m[6] = fmaf(f, c1.z - a1.z, a1.z);
        m[7] = fmaf(f, c1.w - a1.w, a1.w);
        m[8] = fmaf(f, c2.x - a2.x, a2.x);
        m[9] = fmaf(f, c2.y - a2.y, a2.y);

        int idx = (int)d; if (idx > 9) idx = 9;

        const float4* xdp = (const float4*)(x + (size_t)dst * 2 * HD);
        #pragma unroll
        for (int q = 0; q < 5; ++q) {
            float4 xv = xdp[q];
            #pragma unroll
            for (int t = 0; t < 4; ++t) {
                const int k = 4 * q + t;
                float xdk = (t == 0) ? xv.x : (t == 1) ? xv.y : (t == 2) ? xv.z : xv.w;
                float base = fabsf(a * xs[k] - oma * xdk);
                float rho = (base > 0.0f) ? exp2f(bb * log2f(base)) : 0.0f;
                Sr[k] += rho;
                float comb;
                if (k < 10) comb = (k == idx) ? 1.0f : 0.0f;
                else        comb = fmaxf(m[k - 10], 0.0f);
                S0[k] += comb;
                S1[k] = fmaf(rho, comb, S1[k]);
            }
        }
    }

    #pragma unroll
    for (int s = 8; s >= 1; s >>= 1) {
        #pragma unroll
        for (int k = 0; k < HD; ++k) {
            S0[k] += __shfl_xor(S0[k], s, 16);
            S1[k] += __shfl_xor(S1[k], s, 16);
            Sr[k] += __shfl_xor(Sr[k], s, 16);
        }
    }

    float sf[HD];
    #pragma unroll
    for (int k = 0; k < HD; ++k)
        sf[k] = (S0[k] != 0.0f) ? (S1[k] / S0[k]) : (0.01f * Sr[k]);

    float* op = out + (size_t)node * 2 * HD;
    {
        int r = lane;                       // rows 0..15
        float acc = bias[r];
        const float4* g1p = (const float4*)(g1 + r * HD);
        const float4* g2p = (const float4*)(g2 + r * HD);
        #pragma unroll
        for (int q = 0; q < 5; ++q) {
            float4 w1 = g1p[q], w2 = g2p[q];
            acc = fmaf(xs[4 * q], w1.x, acc); acc = fmaf(sf[4 * q], w2.x, acc);
            acc = fmaf(xs[4 * q + 1], w1.y, acc); acc = fmaf(sf[4 * q + 1], w2.y, acc);
            acc = fmaf(xs[4 * q + 2], w1.z, acc); acc = fmaf(sf[4 * q + 2], w2.z, acc);
            acc = fmaf(xs[4 * q + 3], w1.w, acc); acc = fmaf(sf[4 * q + 3], w2.w, acc);
        }
        float myv = 0.0f;
        #pragma unroll
        for (int k = 0; k < HD; ++k) if (r == k) myv = sf[k];
        op[r] = fmaxf(acc, 0.0f);
        op[HD + r] = myv;
    }
    if (lane < HD - 16) {                   // rows 16..19 on lanes 0..3
        int r = lane + 16;
        float acc = bias[r];
        const float4* g1p = (const float4*)(g1 + r * HD);
        const float4* g2p = (const float4*)(g2 + r * HD);
        #pragma unroll
        for (int q = 0; q < 5; ++q) {
            float4 w1 = g1p[q], w2 = g2p[q];
            acc = fmaf(xs[4 * q], w1.x, acc); acc = fmaf(sf[4 * q], w2.x, acc);
            acc = fmaf(xs[4 * q + 1], w1.y, acc); acc = fmaf(sf[4 * q + 1], w2.y, acc);
            acc = fmaf(xs[4 * q + 2], w1.z, acc); acc = fmaf(sf[4 * q + 2], w2.z, acc);
            acc = fmaf(xs[4 * q + 3], w1.w, acc); acc = fmaf(sf[4 * q + 3], w2.w, acc);
        }
        float myv = 0.0f;
        #pragma unroll
        for (int k = 0; k < HD; ++k) if (r == k) myv = sf[k];
        op[r] = fmaxf(acc, 0.0f);
        op[HD + r] = myv;
    }
}

extern "C" void kernel_launch(void* const* d_in, const int* in_sizes, int n_in,
                              void* d_out, int out_size, void* d_ws, size_t ws_size,
                              hipStream_t stream) {
    const float* x    = (const float*)d_in[0];
    const int*   ei   = (const int*)d_in[1];
    const float* ea   = (const float*)d_in[2];
    const float* pa   = (const float*)d_in[3];
    const float* pb   = (const float*)d_in[4];
    const float* g1   = (const float*)d_in[5];
    const float* g2   = (const float*)d_in[6];
    const float* bias = (const float*)d_in[7];
    const float* W1   = (const float*)d_in[8];
    const float* b1   = (const float*)d_in[9];
    const float* W2   = (const float*)d_in[10];
    const float* b2   = (const float*)d_in[11];
    float* out = (float*)d_out;

    // workspace layout (all segments 128B-aligned)
    char* ws = (char*)d_ws;
    int*   offsets = (int*)ws;     ws += ((NN + 1) * 4 + 127) / 128 * 128;
    int*   bsum    = (int*)ws;     ws += (NBLK * 4 + 127) / 128 * 128;
    int*   cnt     = (int*)ws;     ws += ((size_t)NN * 4 + 127) / 128 * 128;
    int*   rank    = (int*)ws;     ws += (size_t)NE * 4;
    int2*  csr_pk  = (int2*)ws;    ws += (size_t)NE * 8;
    float* tab     = (float*)ws;   ws += (size_t)(TBINS + 2) * TROW * 4;

    zero_ints<<<(NN + 255) / 256, 256, 0, stream>>>(cnt, NN);
    table_kernel<<<(TBINS + 256) / 256, 256, 0, stream>>>(W1, b1, W2, b2, tab);
    hist_rank_kernel<<<(NE + 255) / 256, 256, 0, stream>>>(ei, cnt, rank);
    scanA_kernel<<<NBLK, SCAN_B, 0, stream>>>(cnt, offsets, bsum);
    scanB_kernel<<<1, 64, 0, stream>>>(bsum, offsets);
    scanC_kernel<<<(NN + 255) / 256, 256, 0, stream>>>(offsets, bsum);
    scatter_kernel<<<(NE + 255) / 256, 256, 0, stream>>>(ei, ea, offsets, rank, csr_pk);
    node_kernel<<<(NN + 15) / 16, 256, 0, stream>>>(offsets, csr_pk, x, tab,
                                                    pa, pb, g1, g2, bias, out);
}

// Round 9
// 320.254 us; speedup vs baseline: 8.9922x; 1.0267x over previous
//
#include <hip/hip_runtime.h>

#define NN 100000
#define NE 3200000
#define HD 20
#define EHD 64
#define EOUTD 10
#define SCAN_B 1024
#define NBLK ((NN + SCAN_B - 1) / SCAN_B)   // 98
#define TBINS 4096
#define TROW 12                              // 10 values + 2 pad -> 48B rows

// ---------------- zero int buffer ----------------
__global__ void zero_ints(int* __restrict__ p, int n) {
    int i = blockIdx.x * blockDim.x + threadIdx.x;
    if (i < n) p[i] = 0;
}

// ---------------- histogram of src + per-edge rank ----------------
__global__ void hist_rank_kernel(const int* __restrict__ ei,
                                 int* __restrict__ cnt,
                                 int* __restrict__ rank) {
    int e = blockIdx.x * blockDim.x + threadIdx.x;
    if (e >= NE) return;
    rank[e] = atomicAdd(&cnt[ei[e]], 1);
}

// ---------------- scan A ----------------
__global__ void scanA_kernel(const int* __restrict__ cnt,
                             int* __restrict__ offsets,
                             int* __restrict__ bsum) {
    __shared__ int s[SCAN_B];
    int t = threadIdx.x;
    int i = blockIdx.x * SCAN_B + t;
    int v = (i < NN) ? cnt[i] : 0;
    s[t] = v;
    __syncthreads();
    for (int off = 1; off < SCAN_B; off <<= 1) {
        int add = (t >= off) ? s[t - off] : 0;
        __syncthreads();
        s[t] += add;
        __syncthreads();
    }
    int incl = s[t];
    if (i < NN) offsets[i] = incl - v;
    if (t == SCAN_B - 1) bsum[blockIdx.x] = incl;
}

// ---------------- scan B ----------------
__global__ void scanB_kernel(int* __restrict__ bsum, int* __restrict__ offsets) {
    if (blockIdx.x == 0 && threadIdx.x == 0) {
        int run = 0;
        for (int b = 0; b < NBLK; ++b) {
            int t = bsum[b];
            bsum[b] = run;
            run += t;
        }
        offsets[NN] = run;
    }
}

// ---------------- scan C ----------------
__global__ void scanC_kernel(int* __restrict__ offsets,
                             const int* __restrict__ bsum) {
    int i = blockIdx.x * blockDim.x + threadIdx.x;
    if (i >= NN) return;
    offsets[i] += bsum[i >> 10];
}

// ---------------- MLP table ----------------
__global__ void table_kernel(const float* __restrict__ W1,
                             const float* __restrict__ b1,
                             const float* __restrict__ W2,
                             const float* __restrict__ b2,
                             float* __restrict__ tab) {
    int i = blockIdx.x * blockDim.x + threadIdx.x;
    if (i > TBINS) return;
    float d = (float)i * (10.0f / (float)TBINS);
    float m[EOUTD];
    #pragma unroll
    for (int j = 0; j < EOUTD; ++j) m[j] = b2[j];
    for (int k = 0; k < EHD; ++k) {
        float h = fmaxf(fmaf(d, W1[k], b1[k]), 0.0f);
        #pragma unroll
        for (int j = 0; j < EOUTD; ++j) m[j] = fmaf(h, W2[k * EOUTD + j], m[j]);
    }
    float* row = tab + (size_t)i * TROW;
    #pragma unroll
    for (int j = 0; j < EOUTD; ++j) row[j] = m[j];
    row[10] = 0.0f; row[11] = 0.0f;
}

// ---------------- bf16-pack x[:,0,:] into 64B line-aligned rows ----------
__global__ void xbf_kernel(const float* __restrict__ x,
                           unsigned short* __restrict__ xbf) {
    int t = blockIdx.x * blockDim.x + threadIdx.x;
    if (t >= NN * 16) return;
    int node = t >> 4;
    int j = (t & 15) * 2;
    float f0 = (j < HD)     ? x[(size_t)node * 2 * HD + j]     : 0.0f;
    float f1 = (j + 1 < HD) ? x[(size_t)node * 2 * HD + j + 1] : 0.0f;
    unsigned int u0 = __float_as_uint(f0);
    unsigned int u1 = __float_as_uint(f1);
    u0 = (u0 + 0x7fffu + ((u0 >> 16) & 1u)) >> 16;   // RNE bf16
    u1 = (u1 + 0x7fffu + ((u1 >> 16) & 1u)) >> 16;
    ushort2 p;
    p.x = (unsigned short)u0;
    p.y = (unsigned short)u1;
    *(ushort2*)(xbf + (size_t)node * 32 + j) = p;
}

// ---------------- scatter edges into packed CSR (no atomics) ----------------
__global__ void scatter_kernel(const int* __restrict__ ei,
                               const float* __restrict__ ea,
                               const int* __restrict__ offsets,
                               const int* __restrict__ rank,
                               int2* __restrict__ csr_pk) {
    int e = blockIdx.x * blockDim.x + threadIdx.x;
    if (e >= NE) return;
    int src = ei[e];
    int pos = offsets[src] + rank[e];
    int2 pk;
    pk.x = ei[NE + e];
    pk.y = __float_as_int(ea[e]);
    csr_pk[pos] = pk;
}

// ---------------- node-owner kernel ----------------
__launch_bounds__(256)
__global__ void node_kernel(const int* __restrict__ offsets,
                            const int2* __restrict__ csr_pk,
                            const float* __restrict__ x,
                            const unsigned short* __restrict__ xbf,
                            const float* __restrict__ tab,
                            const float* __restrict__ pa,
                            const float* __restrict__ pb,
                            const float* __restrict__ g1,
                            const float* __restrict__ g2,
                            const float* __restrict__ bias,
                            float* __restrict__ out) {
    int tid  = threadIdx.x;
    int grp  = tid >> 4;          // 16 nodes per 256-thread block
    int lane = tid & 15;
    int node = blockIdx.x * 16 + grp;
    if (node >= NN) return;

    int off0 = offsets[node];
    int deg  = offsets[node + 1] - off0;
    float a = pa[0], bb = pb[0];
    float oma = 1.0f - a;

    // axs[k] = a * x[node,0,k]
    float axs[HD];
    {
        const float4* xp = (const float4*)(x + (size_t)node * 2 * HD);
        #pragma unroll
        for (int q = 0; q < 5; ++q) {
            float4 v = xp[q];
            axs[4 * q] = a * v.x; axs[4 * q + 1] = a * v.y;
            axs[4 * q + 2] = a * v.z; axs[4 * q + 3] = a * v.w;
        }
    }

    float S0[HD], S1[HD], Sr[HD];
    #pragma unroll
    for (int k = 0; k < HD; ++k) { S0[k] = 0.0f; S1[k] = 0.0f; Sr[k] = 0.0f; }

    // per-edge accumulate: d + one bf16 row (3 int4 = 24 bf16, first 20 used)
    auto edge = [&](float d, int4 w0, int4 w1, int4 w2) {
        float u = d * ((float)TBINS / 10.0f);
        int ti = (int)u; if (ti > TBINS - 1) ti = TBINS - 1;
        float fr = u - (float)ti;
        const float4* t0 = (const float4*)(tab + (size_t)ti * TROW);
        float4 a0 = t0[0], a1 = t0[1], a2 = t0[2];
        float4 c0 = t0[3], c1 = t0[4], c2 = t0[5];
        float m[EOUTD];
        m[0] = fmaf(fr, c0.x - a0.x, a0.x);
        m[1] = fmaf(fr, c0.y - a0.y, a0.y);
        m[2] = fmaf(fr, c0.z - a0.z, a0.z);
        m[3] = fmaf(fr, c0.w - a0.w, a0.w);
        m[4] = fmaf(fr, c1.x - a1.x, a1.x);
        m[5] = fmaf(fr, c1.y - a1.y, a1.y);
        m[6] = fmaf(fr, c1.z - a1.z, a1.z);
        m[7] = fmaf(fr, c1.w - a1.w, a1.w);
        m[8] = fmaf(fr, c2.x - a2.x, a2.x);
        m[9] = fmaf(fr, c2.y - a2.y, a2.y);
        int idx = (int)d; if (idx > 9) idx = 9;

        int w[5];
        w[0] = w0.x; w[1] = w0.y; w[2] = w0.z; w[3] = w0.w;
        w[4] = w1.x;   // k=16..19 come from w1.x/.y below
        int w5 = w1.y;
        #pragma unroll
        for (int p = 0; p < 5; ++p) {
            int wp = w[p];
            float xlo = __uint_as_float(((unsigned int)wp) << 16);
            float xhi = __uint_as_float(((unsigned int)wp) & 0xffff0000u);
            #pragma unroll
            for (int h = 0; h < 2; ++h) {
                const int k = 2 * p + h;
                float xdk = h ? xhi : xlo;
                float t = fmaf(-oma, xdk, axs[k]);
                float rho = (t != 0.0f) ? exp2f(bb * log2f(fabsf(t))) : 0.0f;
                Sr[k] += rho;
                float comb = (k == idx) ? 1.0f : 0.0f;
                S0[k] += comb;
                S1[k] = fmaf(rho, comb, S1[k]);
            }
        }
        {
            float xlo = __uint_as_float(((unsigned int)w5) << 16);
            float xhi = __uint_as_float(((unsigned int)w5) & 0xffff0000u);
            // k = 10, 11
            #pragma unroll
            for (int h = 0; h < 2; ++h) {
                const int k = 10 + h;
                float xdk = h ? xhi : xlo;
                float t = fmaf(-oma, xdk, axs[k]);
                float rho = (t != 0.0f) ? exp2f(bb * log2f(fabsf(t))) : 0.0f;
                Sr[k] += rho;
                float comb = fmaxf(m[k - 10], 0.0f);
                S0[k] += comb;
                S1[k] = fmaf(rho, comb, S1[k]);
            }
        }
        int w6[4];
        w6[0] = w1.z; w6[1] = w1.w; w6[2] = w2.x; w6[3] = w2.y;
        #pragma unroll
        for (int p = 0; p < 4; ++p) {
            int wp = w6[p];
            float xlo = __uint_as_float(((unsigned int)wp) << 16);
            float xhi = __uint_as_float(((unsigned int)wp) & 0xffff0000u);
            #pragma unroll
            for (int h = 0; h < 2; ++h) {
                const int k = 12 + 2 * p + h;
                float xdk = h ? xhi : xlo;
                float t = fmaf(-oma, xdk, axs[k]);
                float rho = (t != 0.0f) ? exp2f(bb * log2f(fabsf(t))) : 0.0f;
                Sr[k] += rho;
                float comb = fmaxf(m[k - 10], 0.0f);
                S0[k] += comb;
                S1[k] = fmaf(rho, comb, S1[k]);
            }
        }
    };

    // batched first 2 strides: all loads issued up front
    {
        bool v0 = lane < deg;
        bool v1 = lane + 16 < deg;
        int p0 = v0 ? (off0 + lane) : off0;
        int p1 = v1 ? (off0 + lane + 16) : off0;
        if (p0 > NE - 1) p0 = NE - 1;
        if (p1 > NE - 1) p1 = NE - 1;
        int2 pk0 = csr_pk[p0];
        int2 pk1 = csr_pk[p1];
        const int4* r0 = (const int4*)(xbf + (size_t)(unsigned int)pk0.x * 32);
        const int4* r1 = (const int4*)(xbf + (size_t)(unsigned int)pk1.x * 32);
        int4 A0 = r0[0], A1 = r0[1], A2 = r0[2];
        int4 B0 = r1[0], B1 = r1[1], B2 = r1[2];
        if (v0) edge(__int_as_float(pk0.y), A0, A1, A2);
        if (v1) edge(__int_as_float(pk1.y), B0, B1, B2);
    }
    // rare tail (deg > 32)
    for (int i = lane + 32; i < deg; i += 16) {
        int2 pk = csr_pk[off0 + i];
        const int4* r = (const int4*)(xbf + (size_t)(unsigned int)pk.x * 32);
        int4 A0 = r[0], A1 = r[1], A2 = r[2];
        edge(__int_as_float(pk.y), A0, A1, A2);
    }

    #pragma unroll
    for (int s = 8; s >= 1; s >>= 1) {
        #pragma unroll
        for (int k = 0; k < HD; ++k) {
            S0[k] += __shfl_xor(S0[k], s, 16);
            S1[k] += __shfl_xor(S1[k], s, 16);
            Sr[k] += __shfl_xor(Sr[k], s, 16);
        }
    }

    float sf[HD];
    #pragma unroll
    for (int k = 0; k < HD; ++k)
        sf[k] = (S0[k] != 0.0f) ? (S1[k] / S0[k]) : (0.01f * Sr[k]);

    // re-read x row (f32) for the g1 term
    float xs[HD];
    {
        const float4* xp = (const float4*)(x + (size_t)node * 2 * HD);
        #pragma unroll
        for (int q = 0; q < 5; ++q) {
            float4 v = xp[q];
            xs[4 * q] = v.x; xs[4 * q + 1] = v.y;
            xs[4 * q + 2] = v.z; xs[4 * q + 3] = v.w;
        }
    }

    float* op = out + (size_t)node * 2 * HD;
    {
        int r = lane;                       // rows 0..15
        float acc = bias[r];
        const float4* g1p = (const float4*)(g1 + r * HD);
        const float4* g2p = (const float4*)(g2 + r * HD);
        #pragma unroll
        for (int q = 0; q < 5; ++q) {
            float4 w1 = g1p[q], w2 = g2p[q];
            acc = fmaf(xs[4 * q], w1.x, acc); acc = fmaf(sf[4 * q], w2.x, acc);
            acc = fmaf(xs[4 * q + 1], w1.y, acc); acc = fmaf(sf[4 * q + 1], w2.y, acc);
            acc = fmaf(xs[4 * q + 2], w1.z, acc); acc = fmaf(sf[4 * q + 2], w2.z, acc);
            acc = fmaf(xs[4 * q + 3], w1.w, acc); acc = fmaf(sf[4 * q + 3], w2.w, acc);
        }
        float myv = 0.0f;
        #pragma unroll
        for (int k = 0; k < HD; ++k) if (r == k) myv = sf[k];
        op[r] = fmaxf(acc, 0.0f);
        op[HD + r] = myv;
    }
    if (lane < HD - 16) {                   // rows 16..19
        int r = lane + 16;
        float acc = bias[r];
        const float4* g1p = (const float4*)(g1 + r * HD);
        const float4* g2p = (const float4*)(g2 + r * HD);
        #pragma unroll
        for (int q = 0; q < 5; ++q) {
            float4 w1 = g1p[q], w2 = g2p[q];
            acc = fmaf(xs[4 * q], w1.x, acc); acc = fmaf(sf[4 * q], w2.x, acc);
            acc = fmaf(xs[4 * q + 1], w1.y, acc); acc = fmaf(sf[4 * q + 1], w2.y, acc);
            acc = fmaf(xs[4 * q + 2], w1.z, acc); acc = fmaf(sf[4 * q + 2], w2.z, acc);
            acc = fmaf(xs[4 * q + 3], w1.w, acc); acc = fmaf(sf[4 * q + 3], w2.w, acc);
        }
        float myv = 0.0f;
        #pragma unroll
        for (int k = 0; k < HD; ++k) if (r == k) myv = sf[k];
        op[r] = fmaxf(acc, 0.0f);
        op[HD + r] = myv;
    }
}

extern "C" void kernel_launch(void* const* d_in, const int* in_sizes, int n_in,
                              void* d_out, int out_size, void* d_ws, size_t ws_size,
                              hipStream_t stream) {
    const float* x    = (const float*)d_in[0];
    const int*   ei   = (const int*)d_in[1];
    const float* ea   = (const float*)d_in[2];
    const float* pa   = (const float*)d_in[3];
    const float* pb   = (const float*)d_in[4];
    const float* g1   = (const float*)d_in[5];
    const float* g2   = (const float*)d_in[6];
    const float* bias = (const float*)d_in[7];
    const float* W1   = (const float*)d_in[8];
    const float* b1   = (const float*)d_in[9];
    const float* W2   = (const float*)d_in[10];
    const float* b2   = (const float*)d_in[11];
    float* out = (float*)d_out;

    // workspace layout (all segments 128B-aligned)
    char* ws = (char*)d_ws;
    int*   offsets = (int*)ws;       ws += ((NN + 1) * 4 + 127) / 128 * 128;
    int*   bsum    = (int*)ws;       ws += (NBLK * 4 + 127) / 128 * 128;
    int*   cnt     = (int*)ws;       ws += ((size_t)NN * 4 + 127) / 128 * 128;
    int*   rank    = (int*)ws;       ws += (size_t)NE * 4;
    int2*  csr_pk  = (int2*)ws;      ws += (size_t)NE * 8;
    float* tab     = (float*)ws;     ws += (size_t)(TBINS + 2) * TROW * 4;
    unsigned short* xbf = (unsigned short*)ws;  ws += (size_t)NN * 32 * 2;

    zero_ints<<<(NN + 255) / 256, 256, 0, stream>>>(cnt, NN);
    table_kernel<<<(TBINS + 256) / 256, 256, 0, stream>>>(W1, b1, W2, b2, tab);
    xbf_kernel<<<(NN * 16 + 255) / 256, 256, 0, stream>>>(x, xbf);
    hist_rank_kernel<<<(NE + 255) / 256, 256, 0, stream>>>(ei, cnt, rank);
    scanA_kernel<<<NBLK, SCAN_B, 0, stream>>>(cnt, offsets, bsum);
    scanB_kernel<<<1, 64, 0, stream>>>(bsum, offsets);
    scanC_kernel<<<(NN + 255) / 256, 256, 0, stream>>>(offsets, bsum);
    scatter_kernel<<<(NE + 255) / 256, 256, 0, stream>>>(ei, ea, offsets, rank, csr_pk);
    node_kernel<<<(NN + 15) / 16, 256, 0, stream>>>(offsets, csr_pk, x, xbf, tab,
                                                    pa, pb, g1, g2, bias, out);
}